// Round 3
// baseline (366.402 us; speedup 1.0000x reference)
//
#include <hip/hip_runtime.h>
#include <hip/hip_bf16.h>
#include <cstdint>
#include <cstddef>

#define BB 8
#define TT 2048
#define CC 2048
#define EE 32
#define HH 64
#define KC 4   // gemm1 split-K

typedef __bf16 v8bf __attribute__((ext_vector_type(8)));
typedef float v4f __attribute__((ext_vector_type(4)));

// async global->LDS, 16B per lane; LDS dest is wave-uniform base + lane*16 (HW rule)
#define GLOAD16(gp, lp)                                                              \
  __builtin_amdgcn_global_load_lds((const __attribute__((address_space(1))) void*)(gp), \
                                   (__attribute__((address_space(3))) void*)(lp), 16, 0, 0)

__device__ __forceinline__ unsigned short bf16r(float x) {
    __hip_bfloat16 h = __float2bfloat16(x);
    return *(unsigned short*)&h;
}

// ---------------- kernel 1: token partial sums + bf16 conversion (one pass over hs) ----
// grid (B*C/1024, 8), block 256; each thread: 4 columns x 256 tokens, float4 loads.
__global__ void k_convsum(const float* __restrict__ hs, __hip_bfloat16* __restrict__ hsb,
                          float* __restrict__ partial) {
    int idx4 = blockIdx.x * 256 + threadIdx.x;       // over B*C/4
    int chunk = blockIdx.y;                          // 0..7
    int b = idx4 >> 9;                               // C/4 = 512 per batch
    int c = (idx4 & 511) * 4;
    const float* p = hs + (size_t)b * TT * CC + (size_t)chunk * (TT / 8) * CC + c;
    __hip_bfloat16* q = hsb + (size_t)b * TT * CC + (size_t)chunk * (TT / 8) * CC + c;
    float s0 = 0.f, s1 = 0.f, s2 = 0.f, s3 = 0.f;
    #pragma unroll 8
    for (int t = 0; t < TT / 8; ++t) {
        float4 v = *(const float4*)(p + (size_t)t * CC);
        s0 += v.x; s1 += v.y; s2 += v.z; s3 += v.w;
        ushort4 u;
        u.x = bf16r(v.x); u.y = bf16r(v.y); u.z = bf16r(v.z); u.w = bf16r(v.w);
        *(ushort4*)(q + (size_t)t * CC) = u;
    }
    float4 ps = make_float4(s0, s1, s2, s3);
    *(float4*)(partial + (size_t)chunk * (BB * CC) + (size_t)b * CC + c) = ps;
}

// ---------------- kernel 2: affinity logits, one block per (e,b) ----------------
// 1/T mean factor cancels in the cosine normalization -> skipped
__global__ void k_affinity(const float* __restrict__ partial, const float* __restrict__ sim,
                           const float* __restrict__ gates, float* __restrict__ logits) {
    __shared__ float red[256];
    int e = blockIdx.x, b = blockIdx.y, tid = threadIdx.x;
    float d = 0.f, n = 0.f, m2 = 0.f;
    for (int c = tid; c < CC; c += 256) {
        float sr = 0.f;
        #pragma unroll
        for (int ch = 0; ch < 8; ++ch) sr += partial[(size_t)ch * (BB * CC) + b * CC + c];
        float sv = sim[(size_t)c * EE + e];
        d += sr * sv; n += sv * sv; m2 += sr * sr;
    }
    red[tid] = d; __syncthreads();
    for (int s = 128; s > 0; s >>= 1) { if (tid < s) red[tid] += red[tid + s]; __syncthreads(); }
    d = red[0]; __syncthreads();
    red[tid] = n; __syncthreads();
    for (int s = 128; s > 0; s >>= 1) { if (tid < s) red[tid] += red[tid + s]; __syncthreads(); }
    n = red[0]; __syncthreads();
    red[tid] = m2; __syncthreads();
    for (int s = 128; s > 0; s >>= 1) { if (tid < s) red[tid] += red[tid + s]; __syncthreads(); }
    m2 = red[0];
    if (tid == 0) {
        float aff = d * rsqrtf(n) * rsqrtf(m2);
        float sg = 1.0f / (1.0f + expf(-gates[e]));
        logits[b * EE + e] = aff - sg;
    }
}

// ---------------- kernel 3: mask/fallback/softmax -> routing (B,E) ----------------
__global__ void k_route(const float* __restrict__ logits, float* __restrict__ routing) {
    int b = threadIdx.x;
    if (b >= BB) return;
    float lg[EE], gated[EE];
    int mask[EE];
    int nact = 0;
    for (int e = 0; e < EE; ++e) {
        lg[e] = logits[b * EE + e];
        float g = lg[e] > 0.f ? lg[e] : 0.f;
        gated[e] = g;
        mask[e] = (g > 0.f) ? 1 : 0;
        nact += mask[e];
    }
    if (nact == 0) {
        int chosen[EE];
        for (int e = 0; e < EE; ++e) chosen[e] = 0;
        for (int k = 0; k < EE / 2; ++k) {   // stable top-k: strict > keeps lowest index on ties
            int best = -1; float bv = 0.f;
            for (int e = 0; e < EE; ++e) {
                if (chosen[e]) continue;
                if (best < 0 || lg[e] > bv) { best = e; bv = lg[e]; }
            }
            chosen[best] = 1;
        }
        for (int e = 0; e < EE; ++e) mask[e] = chosen[e];
    }
    float m = -3.402823466e+38f;
    for (int e = 0; e < EE; ++e)
        if (mask[e] && gated[e] > m) m = gated[e];
    float ssum = 0.f; float ex[EE];
    for (int e = 0; e < EE; ++e) {
        float v = mask[e] ? expf(gated[e] - m) : 0.f;
        ex[e] = v; ssum += v;
    }
    float inv = 1.0f / ssum;
    for (int e = 0; e < EE; ++e) routing[b * EE + e] = ex[e] * inv;
}

// ---------------- kernel 4a: wve[b][h][c] = sum_e r[b][e]*w_v[e][h][c] (bf16) ----------
// grid (H*C/256), block 256
__global__ void k_wmix_v(const float* __restrict__ w_v, const float* __restrict__ routing,
                         __hip_bfloat16* __restrict__ wve) {
    __shared__ float r[BB * EE];
    int tid = threadIdx.x;
    r[tid] = routing[tid];
    __syncthreads();
    size_t idx = (size_t)blockIdx.x * 256 + tid;
    float acc[BB] = {};
    for (int e = 0; e < EE; ++e) {
        float v = w_v[(size_t)e * HH * CC + idx];
        #pragma unroll
        for (int b = 0; b < BB; ++b) acc[b] += r[b * EE + e] * v;
    }
    #pragma unroll
    for (int b = 0; b < BB; ++b) wve[(size_t)b * HH * CC + idx] = __float2bfloat16(acc[b]);
}

// ---------------- kernel 4b: woe_t[b][d][h] = sum_e r[b][e]*o_w[e][h][d] (bf16, transposed)
// grid (C/64, B), block 256. LDS transpose so the global write is h-contiguous.
__global__ void k_wmix_o(const float* __restrict__ o_w, const float* __restrict__ routing,
                         __hip_bfloat16* __restrict__ woe_t) {
    __shared__ float rr[EE];
    __shared__ float lt[64 * 65];   // lt[c][h], pad 65 -> conflict-free both phases
    int tid = threadIdx.x;
    int c0 = blockIdx.x * 64, b = blockIdx.y;
    if (tid < EE) rr[tid] = routing[b * EE + tid];
    __syncthreads();
    int c = tid & 63;
    int hb = (tid >> 6) * 16;       // 16 h-values per thread
    float acc[16] = {};
    for (int e = 0; e < EE; ++e) {
        float re = rr[e];
        #pragma unroll
        for (int i = 0; i < 16; ++i) {
            float v = o_w[(size_t)e * HH * CC + (size_t)(hb + i) * CC + c0 + c];
            acc[i] += re * v;
        }
    }
    #pragma unroll
    for (int i = 0; i < 16; ++i) lt[c * 65 + hb + i] = acc[i];
    __syncthreads();
    int h2 = (tid & 31) * 2;
    int cb = tid >> 5;
    #pragma unroll
    for (int k = 0; k < 8; ++k) {
        int cc2 = cb + k * 8;
        unsigned int pk = (unsigned int)bf16r(lt[cc2 * 65 + h2]) |
                          ((unsigned int)bf16r(lt[cc2 * 65 + h2 + 1]) << 16);
        *(unsigned int*)((unsigned short*)woe_t + (size_t)b * CC * HH +
                         (size_t)(c0 + cc2) * HH + h2) = pk;
    }
}

// ---------------- kernel 5: GEMM1 bf16 MFMA: partialC[kc] = hs_bf16 @ wve^T ----------
// grid (T/64, KC, B), block 256. XOR-swizzled LDS (conflict-free b128 + linear GLOAD16).
__global__ __launch_bounds__(256) void k_gemm1(const __hip_bfloat16* __restrict__ A,
                                               const __hip_bfloat16* __restrict__ Bw,
                                               float* __restrict__ partialC) {
    __shared__ __align__(16) __hip_bfloat16 Asm[64 * 64];
    __shared__ __align__(16) __hip_bfloat16 Bsm[64 * 64];
    int tid = threadIdx.x;
    int t0 = blockIdx.x * 64;
    int kc = blockIdx.y;
    int b  = blockIdx.z;
    const __hip_bfloat16* Ag = A + (size_t)b * TT * CC + (size_t)t0 * CC;
    const __hip_bfloat16* Bg = Bw + (size_t)b * HH * CC;
    int wv = tid >> 6, lane = tid & 63, lm = lane & 15, quad = lane >> 4;
    int L0 = tid, L1 = tid + 256;
    int row0 = L0 >> 3, c0 = ((L0 & 7) ^ (row0 & 7)) * 8;
    int row1 = L1 >> 3, c1 = ((L1 & 7) ^ (row1 & 7)) * 8;
    char* AsmB = (char*)Asm;
    char* BsmB = (char*)Bsm;
    int ldsoff0 = (wv * 64 + lane) * 16;
    int ldsoff1 = (256 + wv * 64 + lane) * 16;
    v4f acc[4] = {};
    int kend = kc * (CC / KC) + CC / KC;
    for (int kk0 = kc * (CC / KC); kk0 < kend; kk0 += 64) {
        GLOAD16(Ag + (size_t)row0 * CC + kk0 + c0, AsmB + ldsoff0);
        GLOAD16(Ag + (size_t)row1 * CC + kk0 + c1, AsmB + ldsoff1);
        GLOAD16(Bg + (size_t)row0 * CC + kk0 + c0, BsmB + ldsoff0);
        GLOAD16(Bg + (size_t)row1 * CC + kk0 + c1, BsmB + ldsoff1);
        __syncthreads();
        int arow = wv * 16 + lm;
        #pragma unroll
        for (int s = 0; s < 2; ++s) {
            v8bf a = *(const v8bf*)(AsmB + (arow * 8 + ((s * 4 + quad) ^ (arow & 7))) * 16);
            #pragma unroll
            for (int j = 0; j < 4; ++j) {
                int brow = j * 16 + lm;
                v8bf bb = *(const v8bf*)(BsmB + (brow * 8 + ((s * 4 + quad) ^ (brow & 7))) * 16);
                acc[j] = __builtin_amdgcn_mfma_f32_16x16x32_bf16(a, bb, acc[j], 0, 0, 0);
            }
        }
        __syncthreads();
    }
    float* Cp = partialC + ((size_t)kc * BB + b) * TT * HH + (size_t)t0 * HH;
    #pragma unroll
    for (int j = 0; j < 4; ++j)
        #pragma unroll
        for (int r2 = 0; r2 < 4; ++r2)
            Cp[(size_t)(wv * 16 + quad * 4 + r2) * HH + j * 16 + lm] = acc[j][r2];
}

// ---------------- kernel 6: split-K reduce -> combined bf16 (vectorized) ----------------
__global__ void k_reduce(const float* __restrict__ pC, __hip_bfloat16* __restrict__ comb) {
    size_t i4 = ((size_t)blockIdx.x * 256 + threadIdx.x) * 4;
    const size_t S = (size_t)BB * TT * HH;
    float4 a = *(const float4*)(pC + i4);
    float4 b = *(const float4*)(pC + i4 + S);
    float4 c = *(const float4*)(pC + i4 + 2 * S);
    float4 d = *(const float4*)(pC + i4 + 3 * S);
    ushort4 u;
    u.x = bf16r(a.x + b.x + c.x + d.x);
    u.y = bf16r(a.y + b.y + c.y + d.y);
    u.z = bf16r(a.z + b.z + c.z + d.z);
    u.w = bf16r(a.w + b.w + c.w + d.w);
    *(ushort4*)((unsigned short*)comb + i4) = u;
}

// ---------------- kernel 7: GEMM2 bf16 MFMA: out = comb @ woe_t^T ----------------
// grid (C/64, T/64, B), block 256. K=64 single shot, both tiles via GLOAD16 + XOR swizzle.
__global__ __launch_bounds__(256) void k_gemm2(const __hip_bfloat16* __restrict__ comb,
                                               const __hip_bfloat16* __restrict__ WoT,
                                               float* __restrict__ out) {
    __shared__ __align__(16) __hip_bfloat16 Asm[64 * 64];
    __shared__ __align__(16) __hip_bfloat16 Bsm[64 * 64];
    int tid = threadIdx.x;
    int d0 = blockIdx.x * 64, t0 = blockIdx.y * 64, b = blockIdx.z;
    const __hip_bfloat16* Ag = comb + (size_t)b * TT * HH + (size_t)t0 * HH;   // rows [t][h]
    const __hip_bfloat16* Bg = WoT + (size_t)b * CC * HH + (size_t)d0 * HH;    // rows [d][h]
    int wv = tid >> 6, lane = tid & 63, lm = lane & 15, quad = lane >> 4;
    int L0 = tid, L1 = tid + 256;
    int row0 = L0 >> 3, c0 = ((L0 & 7) ^ (row0 & 7)) * 8;
    int row1 = L1 >> 3, c1 = ((L1 & 7) ^ (row1 & 7)) * 8;
    char* AsmB = (char*)Asm;
    char* BsmB = (char*)Bsm;
    int ldsoff0 = (wv * 64 + lane) * 16;
    int ldsoff1 = (256 + wv * 64 + lane) * 16;
    GLOAD16(Ag + (size_t)row0 * HH + c0, AsmB + ldsoff0);
    GLOAD16(Ag + (size_t)row1 * HH + c1, AsmB + ldsoff1);
    GLOAD16(Bg + (size_t)row0 * HH + c0, BsmB + ldsoff0);
    GLOAD16(Bg + (size_t)row1 * HH + c1, BsmB + ldsoff1);
    __syncthreads();
    v4f acc[4] = {};
    int arow = wv * 16 + lm;
    #pragma unroll
    for (int s = 0; s < 2; ++s) {
        v8bf a = *(const v8bf*)(AsmB + (arow * 8 + ((s * 4 + quad) ^ (arow & 7))) * 16);
        #pragma unroll
        for (int j = 0; j < 4; ++j) {
            int brow = j * 16 + lm;
            v8bf bb = *(const v8bf*)(BsmB + (brow * 8 + ((s * 4 + quad) ^ (brow & 7))) * 16);
            acc[j] = __builtin_amdgcn_mfma_f32_16x16x32_bf16(a, bb, acc[j], 0, 0, 0);
        }
    }
    float* Og = out + (size_t)b * TT * CC + (size_t)t0 * CC + d0;
    #pragma unroll
    for (int j = 0; j < 4; ++j)
        #pragma unroll
        for (int r2 = 0; r2 < 4; ++r2)
            Og[(size_t)(wv * 16 + quad * 4 + r2) * CC + j * 16 + lm] = acc[j][r2];
}

extern "C" void kernel_launch(void* const* d_in, const int* in_sizes, int n_in,
                              void* d_out, int out_size, void* d_ws, size_t ws_size,
                              hipStream_t stream) {
    const float* hs    = (const float*)d_in[0];   // (B,T,C)
    const float* sim   = (const float*)d_in[1];   // (C,E)
    const float* gates = (const float*)d_in[2];   // (E,)
    // d_in[3]=w_q, d_in[4]=w_k: dead (seq_len-1 SDPA == identity on v)
    const float* w_v   = (const float*)d_in[5];   // (E,H,C)
    const float* o_w   = (const float*)d_in[6];   // (E,H,C)
    float* out = (float*)d_out;
    float* ws  = (float*)d_ws;

    // workspace layout (float units)
    size_t o = 0;
    float* partial = ws + o;                          o += (size_t)8 * BB * CC;        // 131072
    float* logits  = ws + o;                          o += BB * EE;
    float* routing = ws + o;                          o += BB * EE;
    float* partialC = ws + o;                         o += (size_t)KC * BB * TT * HH;  // 16 MB
    __hip_bfloat16* comb  = (__hip_bfloat16*)(ws + o); o += (size_t)BB * TT * HH / 2;
    __hip_bfloat16* wve   = (__hip_bfloat16*)(ws + o); o += (size_t)BB * HH * CC / 2;
    __hip_bfloat16* woe_t = (__hip_bfloat16*)(ws + o); o += (size_t)BB * HH * CC / 2;
    size_t f_hsb = (size_t)BB * TT * CC / 2;          // 67 MB in float units
    bool big = ws_size >= (o + f_hsb) * sizeof(float);
    // small-ws fallback: hs_bf16 overlays the front of d_out (gemm2 fully overwrites out later)
    __hip_bfloat16* hsb = big ? (__hip_bfloat16*)(ws + o) : (__hip_bfloat16*)d_out;

    hipLaunchKernelGGL(k_convsum, dim3(BB * CC / 1024, 8), dim3(256), 0, stream,
                       hs, hsb, partial);
    hipLaunchKernelGGL(k_affinity, dim3(EE, BB), dim3(256), 0, stream,
                       partial, sim, gates, logits);
    hipLaunchKernelGGL(k_route, dim3(1), dim3(64), 0, stream, logits, routing);
    hipLaunchKernelGGL(k_wmix_v, dim3(HH * CC / 256), dim3(256), 0, stream,
                       w_v, routing, wve);
    hipLaunchKernelGGL(k_wmix_o, dim3(CC / 64, BB), dim3(256), 0, stream,
                       o_w, routing, woe_t);
    hipLaunchKernelGGL(k_gemm1, dim3(TT / 64, KC, BB), dim3(256), 0, stream,
                       hsb, wve, partialC);
    hipLaunchKernelGGL(k_reduce, dim3(BB * TT * HH / 1024), dim3(256), 0, stream,
                       partialC, comb);
    hipLaunchKernelGGL(k_gemm2, dim3(CC / 64, TT / 64, BB), dim3(256), 0, stream,
                       comb, woe_t, out);
}